// Round 7
// baseline (85.466 us; speedup 1.0000x reference)
//
#include <hip/hip_runtime.h>
#include <cstdint>

// h_t = f_t * h_{t-1} + (1 - f_t) * z_t over [T=1024, B, H], scan along T.
//
// Producer-consumer wave specialization, 3 waves / block, 64 channels / block:
//   wave0: streams f -> LDS ring (dwordx4 global_load_lds, counted vmcnt)
//   wave1: streams z -> LDS ring (own vmcnt domain)
//   wave2: serial recurrence + coalesced scalar stores (never waits on vmcnt)
// Waves rendezvous once per 16-step phase on a raw s_barrier (no
// __syncthreads -> no compiler vmcnt(0) drain). Loaders order their LDS
// deposits with s_waitcnt vmcnt(4*LA) BEFORE the barrier (FIFO retirement).
// Ring: NSLOT=8 slots (64 KB LDS), lookahead LA=6 (28 ops outstanding/loader).

constexpr int T_STEPS = 1024;
constexpr int BATCH   = 16;                 // timesteps per ring slot
constexpr int NPHASE  = T_STEPS / BATCH;    // 64
constexpr int NSLOT   = 8;                  // ring depth (>= LA+2)
constexpr int LA      = 6;                  // lookahead batches

typedef const __attribute__((address_space(1))) unsigned int* gp1_t;
typedef __attribute__((address_space(3))) unsigned int* lp3_t;

#define SBAR() do {                                        \
    asm volatile("s_barrier" ::: "memory");                \
    __builtin_amdgcn_sched_barrier(0);                     \
} while (0)

__global__ __launch_bounds__(192, 1) void fm_pc(const float* __restrict__ f,
                                                const float* __restrict__ z,
                                                float* __restrict__ h,
                                                int BH) {
    __shared__ float ring[2][NSLOT][BATCH][64];   // [0]=f, [1]=z

    const int wid  = (int)threadIdx.x >> 6;
    const int lane = (int)threadIdx.x & 63;
    const uint64_t stride4 = (uint64_t)BH * 4u;        // bytes per timestep row

    if (wid < 2) {
        // ---------------- loader wave (wid=0 -> f, wid=1 -> z) ----------------
        const char* src = (const char*)(wid == 0 ? f : z)
                        + (uint64_t)blockIdx.x * 256u;
        // lane l covers row (l>>4), bytes (l&15)*16 of the 256 B channel strip;
        // global_load_lds width=16 deposits linearly at lds_base + 16*l.
        const uint64_t lane_off = (uint64_t)(lane >> 4) * stride4
                                + (uint64_t)(lane & 15) * 16u;
        float (*my)[BATCH][64] = ring[wid];

        auto issue = [&](int b) {
            const int s = b % NSLOT;
#pragma unroll
            for (int q = 0; q < 4; ++q) {
                const uint64_t roff = (uint64_t)(b * BATCH + 4 * q) * stride4
                                    + lane_off;
                __builtin_amdgcn_global_load_lds((gp1_t)(const void*)(src + roff),
                                                 (lp3_t)(void*)&my[s][4 * q][0],
                                                 16, 0, 0);
            }
        };

        // Prologue: LA batches in flight (24 ops).
#pragma unroll
        for (int b = 0; b < LA; ++b) issue(b);

#pragma unroll 1
        for (int p = 0; p < NPHASE; ++p) {
            if (p + LA < NPHASE) issue(p + LA);
            // Ensure batch p landed: ops newer than batch p = 4*min(LA, rest).
            const int ahead = (NPHASE - 1 - p < LA) ? (NPHASE - 1 - p) : LA;
            switch (ahead) {
                case 6: asm volatile("s_waitcnt vmcnt(24)" ::: "memory"); break;
                case 5: asm volatile("s_waitcnt vmcnt(20)" ::: "memory"); break;
                case 4: asm volatile("s_waitcnt vmcnt(16)" ::: "memory"); break;
                case 3: asm volatile("s_waitcnt vmcnt(12)" ::: "memory"); break;
                case 2: asm volatile("s_waitcnt vmcnt(8)"  ::: "memory"); break;
                case 1: asm volatile("s_waitcnt vmcnt(4)"  ::: "memory"); break;
                default: asm volatile("s_waitcnt vmcnt(0)" ::: "memory"); break;
            }
            __builtin_amdgcn_sched_barrier(0);
            SBAR();                     // publish batch p to the compute wave
        }
    } else {
        // ---------------- compute + store wave ----------------
        float* hp = h + (size_t)blockIdx.x * 64 + lane;
        float hv = 0.0f;

#pragma unroll 1
        for (int p = 0; p < NPHASE; ++p) {
            SBAR();                     // batch p guaranteed resident in LDS
            const int s = p % NSLOT;
#pragma unroll
            for (int i = 0; i < BATCH; ++i) {
                const float fv = ring[0][s][i][lane];
                const float zv = ring[1][s][i][lane];
                hv = fv * (hv - zv) + zv;        // h = f*h + (1-f)*z
                hp[(size_t)(p * BATCH + i) * (size_t)BH] = hv;
            }
        }
    }
}

// Fallback for unexpected shapes: plain sequential-per-channel scan.
__global__ __launch_bounds__(64) void fm_scan_simple(const float* __restrict__ f,
                                                     const float* __restrict__ z,
                                                     float* __restrict__ h,
                                                     int BH, int T) {
    const int ch = blockIdx.x * blockDim.x + threadIdx.x;
    if (ch >= BH) return;
    const size_t stride = (size_t)BH;
    float hv = 0.0f;
    for (int t = 0; t < T; ++t) {
        const float fv = f[(size_t)t * stride + ch];
        const float zv = z[(size_t)t * stride + ch];
        hv = fv * (hv - zv) + zv;
        h[(size_t)t * stride + ch] = hv;
    }
}

extern "C" void kernel_launch(void* const* d_in, const int* in_sizes, int n_in,
                              void* d_out, int out_size, void* d_ws, size_t ws_size,
                              hipStream_t stream) {
    const float* f = (const float*)d_in[0];
    const float* z = (const float*)d_in[1];
    float*       h = (float*)d_out;

    const int BH = in_sizes[0] / T_STEPS;   // 32*1024 = 32768 channels

    if ((BH % 64) == 0) {
        const int grid = BH / 64;           // 512 blocks, 3 waves each
        fm_pc<<<grid, 192, 0, stream>>>(f, z, h, BH);
    } else {
        const int block = 64;
        const int grid  = (BH + block - 1) / block;
        fm_scan_simple<<<grid, block, 0, stream>>>(f, z, h, BH, T_STEPS);
    }
}

// Round 8
// 67.528 us; speedup vs baseline: 1.2656x; 1.2656x over previous
//
#include <hip/hip_runtime.h>

// h_t = f_t * h_{t-1} + (1 - f_t) * z_t over [T=1024, B, H], scan along T.
// One thread per channel (coalesced across channels), ping-pong register
// batches (R2 structure, best so far), plus NON-TEMPORAL stores for h:
// h is written once and never re-read, so `nt` stores keep the 256 MiB
// Infinity Cache free to retain f+z (which together are exactly 256 MiB)
// across graph replays -> less HBM read traffic feeding the bottleneck.

constexpr int T_STEPS = 1024;
constexpr int BATCH   = 16;   // time steps per register batch

__global__ __launch_bounds__(64) void fm_scan(const float* __restrict__ f,
                                              const float* __restrict__ z,
                                              float* __restrict__ h,
                                              int BH) {
    const int ch = blockIdx.x * blockDim.x + threadIdx.x;
    if (ch >= BH) return;

    const float* fp = f + ch;
    const float* zp = z + ch;
    float*       hp = h + ch;
    const size_t stride = (size_t)BH;

    float fA[BATCH], zA[BATCH], fB[BATCH], zB[BATCH];

    // Prologue: load batch A (t = 0..BATCH-1)
#pragma unroll
    for (int i = 0; i < BATCH; ++i) {
        fA[i] = fp[(size_t)i * stride];
        zA[i] = zp[(size_t)i * stride];
    }
    __builtin_amdgcn_sched_barrier(0);

    float hv = 0.0f;

    for (int t0 = 0; t0 < T_STEPS; t0 += 2 * BATCH) {
        // ---- Phase 1: load batch B (t0+BATCH), compute batch A (t0) ----
        if (t0 + BATCH < T_STEPS) {
#pragma unroll
            for (int i = 0; i < BATCH; ++i) {
                fB[i] = fp[(size_t)(t0 + BATCH + i) * stride];
                zB[i] = zp[(size_t)(t0 + BATCH + i) * stride];
            }
        }
        __builtin_amdgcn_sched_barrier(0);
#pragma unroll
        for (int i = 0; i < BATCH; ++i) {
            // h = f*h + (1-f)*z  ==  f*(h - z) + z
            hv = fA[i] * (hv - zA[i]) + zA[i];
            __builtin_nontemporal_store(hv, &hp[(size_t)(t0 + i) * stride]);
        }
        __builtin_amdgcn_sched_barrier(0);

        // ---- Phase 2: load batch A (t0+2*BATCH), compute batch B ----
        if (t0 + 2 * BATCH < T_STEPS) {
#pragma unroll
            for (int i = 0; i < BATCH; ++i) {
                fA[i] = fp[(size_t)(t0 + 2 * BATCH + i) * stride];
                zA[i] = zp[(size_t)(t0 + 2 * BATCH + i) * stride];
            }
        }
        __builtin_amdgcn_sched_barrier(0);
        if (t0 + BATCH < T_STEPS) {
#pragma unroll
            for (int i = 0; i < BATCH; ++i) {
                hv = fB[i] * (hv - zB[i]) + zB[i];
                __builtin_nontemporal_store(hv, &hp[(size_t)(t0 + BATCH + i) * stride]);
            }
        }
        __builtin_amdgcn_sched_barrier(0);
    }
}

extern "C" void kernel_launch(void* const* d_in, const int* in_sizes, int n_in,
                              void* d_out, int out_size, void* d_ws, size_t ws_size,
                              hipStream_t stream) {
    const float* f = (const float*)d_in[0];
    const float* z = (const float*)d_in[1];
    float*       h = (float*)d_out;

    const int BH = in_sizes[0] / T_STEPS;   // 32*1024 = 32768 channels

    const int block = 64;
    const int grid  = (BH + block - 1) / block;  // 512 blocks -> 2 waves/CU
    fm_scan<<<grid, block, 0, stream>>>(f, z, h, BH);
}